// Round 1
// baseline (1208.254 us; speedup 1.0000x reference)
//
#include <hip/hip_runtime.h>
#include <math.h>

namespace {

constexpr int Bb = 8;
constexpr int Nseq = 1024;
constexpr int Dmodel = 768;
constexpr int Hh = 12;
constexpr int dh = 64;
constexpr int Mrows = Bb * Nseq;      // 8192
constexpr int threeD = 3 * Dmodel;    // 2304
constexpr float kScale = 0.125f;      // 1/sqrt(64)

// ---------------------------------------------------------------------------
// Tiled fp32 GEMM: C[M,N] = A[M,K] @ B[K,N] (+ bias). BM=BN=64, BK=16,
// 256 threads, each computes a 4x4 micro-tile. A staged transposed in LDS.
// Dims must divide tiles (8192/64, 2304/64, 768/64, 768/16 all exact).
// ---------------------------------------------------------------------------
template <int BM, int BN, int BK>
__global__ __launch_bounds__(256)
void gemm_f32(const float* __restrict__ A, const float* __restrict__ B,
              float* __restrict__ C, int Ndim, int Kdim,
              const float* __restrict__ bias) {
  __shared__ float As[BK][BM + 4];  // k-major (transposed) A tile, padded
  __shared__ float Bs[BK][BN];
  const int tid = threadIdx.x;
  const int row0 = blockIdx.y * BM;
  const int col0 = blockIdx.x * BN;
  const int tx = tid & 15;
  const int ty = tid >> 4;
  float acc[4][4] = {};
  for (int k0 = 0; k0 < Kdim; k0 += BK) {
    {  // A tile: 64x16 floats, one float4 per thread, write transposed
      const int r = tid >> 2;
      const int k4 = (tid & 3) * 4;
      const float4 a4 = *reinterpret_cast<const float4*>(
          &A[(size_t)(row0 + r) * Kdim + k0 + k4]);
      As[k4 + 0][r] = a4.x;
      As[k4 + 1][r] = a4.y;
      As[k4 + 2][r] = a4.z;
      As[k4 + 3][r] = a4.w;
    }
    {  // B tile: 16x64 floats, one float4 per thread
      const int kk = tid >> 4;
      const int c4 = (tid & 15) * 4;
      *reinterpret_cast<float4*>(&Bs[kk][c4]) =
          *reinterpret_cast<const float4*>(
              &B[(size_t)(k0 + kk) * Ndim + col0 + c4]);
    }
    __syncthreads();
#pragma unroll
    for (int kk = 0; kk < BK; ++kk) {
      const float4 a4 = *reinterpret_cast<const float4*>(&As[kk][ty * 4]);
      const float4 b4 = *reinterpret_cast<const float4*>(&Bs[kk][tx * 4]);
      const float a[4] = {a4.x, a4.y, a4.z, a4.w};
      const float b[4] = {b4.x, b4.y, b4.z, b4.w};
#pragma unroll
      for (int i = 0; i < 4; ++i)
#pragma unroll
        for (int j = 0; j < 4; ++j) acc[i][j] = fmaf(a[i], b[j], acc[i][j]);
    }
    __syncthreads();
  }
  float4 bv = {0.f, 0.f, 0.f, 0.f};
  if (bias) bv = *reinterpret_cast<const float4*>(&bias[col0 + tx * 4]);
#pragma unroll
  for (int i = 0; i < 4; ++i) {
    const int row = row0 + ty * 4 + i;
    float4 o;
    o.x = acc[i][0] + bv.x;
    o.y = acc[i][1] + bv.y;
    o.z = acc[i][2] + bv.z;
    o.w = acc[i][3] + bv.w;
    *reinterpret_cast<float4*>(&C[(size_t)row * Ndim + col0 + tx * 4]) = o;
  }
}

// ---------------------------------------------------------------------------
// Flash attention, fp32. One block = (b, h, 32 query rows). 256 threads.
// Online softmax over 32-key tiles staged in LDS. qkv layout: [B, N, 3, H, d]
// (row stride 3*768). Output written as [B, N, H*d] = [8192, 768].
// Thread t: scores for row r=t/8, keys (t%8)*4..+3; PV acc row r,
// cols (t%8)*8..+7.
// ---------------------------------------------------------------------------
__global__ __launch_bounds__(256)
void attn_f32(const float* __restrict__ qkv, float* __restrict__ attn_out) {
  constexpr int QB = 32, KB = 32, PAD = 4;
  __shared__ float Qs[QB][dh + PAD];
  __shared__ float Ks[KB][dh + PAD];
  __shared__ float Vs[KB][dh + PAD];
  __shared__ float Ps[QB][KB + 4];
  const int tid = threadIdx.x;
  const int qt = blockIdx.x;
  const int h = blockIdx.y;
  const int b = blockIdx.z;
  const size_t base = (size_t)b * Nseq * threeD + (size_t)h * dh;
  // Load Q tile (32x64): 512 float4, 2 per thread
  for (int f = tid; f < QB * (dh / 4); f += 256) {
    const int r = f >> 4;
    const int d4 = (f & 15) * 4;
    *reinterpret_cast<float4*>(&Qs[r][d4]) = *reinterpret_cast<const float4*>(
        &qkv[base + (size_t)(qt * QB + r) * threeD + d4]);
  }
  const int r = tid >> 3;
  const int kg = tid & 7;
  const int c0 = (tid & 7) * 8;
  float m_run = -INFINITY;
  float l_run = 0.f;
  float acc[8] = {};
  __syncthreads();
  for (int kt = 0; kt < Nseq / KB; ++kt) {
    // Load K and V tiles (each 32x64)
    for (int f = tid; f < KB * (dh / 4); f += 256) {
      const int rr = f >> 4;
      const int d4 = (f & 15) * 4;
      const size_t g = base + (size_t)(kt * KB + rr) * threeD + d4;
      *reinterpret_cast<float4*>(&Ks[rr][d4]) =
          *reinterpret_cast<const float4*>(&qkv[g + Dmodel]);
      *reinterpret_cast<float4*>(&Vs[rr][d4]) =
          *reinterpret_cast<const float4*>(&qkv[g + 2 * Dmodel]);
    }
    __syncthreads();
    // Scores: 4 per thread, dot over d=64
    float s[4] = {};
#pragma unroll
    for (int d4 = 0; d4 < dh; d4 += 4) {
      const float4 q4 = *reinterpret_cast<const float4*>(&Qs[r][d4]);
#pragma unroll
      for (int j = 0; j < 4; ++j) {
        const float4 k4 =
            *reinterpret_cast<const float4*>(&Ks[kg * 4 + j][d4]);
        s[j] = fmaf(q4.x, k4.x, s[j]);
        s[j] = fmaf(q4.y, k4.y, s[j]);
        s[j] = fmaf(q4.z, k4.z, s[j]);
        s[j] = fmaf(q4.w, k4.w, s[j]);
      }
    }
#pragma unroll
    for (int j = 0; j < 4; ++j) s[j] *= kScale;
    // Row max across the 8 lanes handling this row
    float tmax = fmaxf(fmaxf(s[0], s[1]), fmaxf(s[2], s[3]));
    tmax = fmaxf(tmax, __shfl_xor(tmax, 1));
    tmax = fmaxf(tmax, __shfl_xor(tmax, 2));
    tmax = fmaxf(tmax, __shfl_xor(tmax, 4));
    const float m_new = fmaxf(m_run, tmax);
    float p[4];
    float psum = 0.f;
#pragma unroll
    for (int j = 0; j < 4; ++j) {
      p[j] = __expf(s[j] - m_new);
      psum += p[j];
    }
    psum += __shfl_xor(psum, 1);
    psum += __shfl_xor(psum, 2);
    psum += __shfl_xor(psum, 4);
    const float alpha = __expf(m_run - m_new);
    l_run = l_run * alpha + psum;
    m_run = m_new;
#pragma unroll
    for (int j = 0; j < 8; ++j) acc[j] *= alpha;
#pragma unroll
    for (int j = 0; j < 4; ++j) Ps[r][kg * 4 + j] = p[j];
    __syncthreads();
    // PV: acc[r][c0..c0+7] += sum_k P[r][k] * V[k][c]
#pragma unroll 4
    for (int k = 0; k < KB; ++k) {
      const float p0 = Ps[r][k];
      const float4 v0 = *reinterpret_cast<const float4*>(&Vs[k][c0]);
      const float4 v1 = *reinterpret_cast<const float4*>(&Vs[k][c0 + 4]);
      acc[0] = fmaf(p0, v0.x, acc[0]);
      acc[1] = fmaf(p0, v0.y, acc[1]);
      acc[2] = fmaf(p0, v0.z, acc[2]);
      acc[3] = fmaf(p0, v0.w, acc[3]);
      acc[4] = fmaf(p0, v1.x, acc[4]);
      acc[5] = fmaf(p0, v1.y, acc[5]);
      acc[6] = fmaf(p0, v1.z, acc[6]);
      acc[7] = fmaf(p0, v1.w, acc[7]);
    }
    __syncthreads();
  }
  const float inv = 1.f / l_run;
  float4 o0, o1;
  o0.x = acc[0] * inv;
  o0.y = acc[1] * inv;
  o0.z = acc[2] * inv;
  o0.w = acc[3] * inv;
  o1.x = acc[4] * inv;
  o1.y = acc[5] * inv;
  o1.z = acc[6] * inv;
  o1.w = acc[7] * inv;
  float* op = &attn_out[((size_t)b * Nseq + qt * QB + r) * Dmodel + h * dh + c0];
  *reinterpret_cast<float4*>(op) = o0;
  *reinterpret_cast<float4*>(op + 4) = o1;
}

}  // namespace

extern "C" void kernel_launch(void* const* d_in, const int* in_sizes, int n_in,
                              void* d_out, int out_size, void* d_ws,
                              size_t ws_size, hipStream_t stream) {
  (void)in_sizes;
  (void)n_in;
  (void)out_size;
  (void)ws_size;
  const float* x = (const float*)d_in[0];      // [8, 1024, 768]
  const float* Wqkv = (const float*)d_in[1];   // [768, 2304]
  const float* Wproj = (const float*)d_in[2];  // [768, 768]
  const float* bproj = (const float*)d_in[3];  // [768]
  float* out = (float*)d_out;                  // [8, 1024, 768]

  float* qkv = (float*)d_ws;                           // [8192, 2304]
  float* attn = qkv + (size_t)Mrows * threeD;          // [8192, 768]

  // 1) QKV projection: qkv = x @ Wqkv
  gemm_f32<64, 64, 16><<<dim3(threeD / 64, Mrows / 64), dim3(256), 0, stream>>>(
      x, Wqkv, qkv, threeD, Dmodel, nullptr);
  // 2) Multi-head flash attention -> [B, N, H*d]
  attn_f32<<<dim3(Nseq / 32, Hh, Bb), dim3(256), 0, stream>>>(qkv, attn);
  // 3) Output projection: out = attn @ Wproj + bproj
  gemm_f32<64, 64, 16><<<dim3(Dmodel / 64, Mrows / 64), dim3(256), 0, stream>>>(
      attn, Wproj, out, Dmodel, Dmodel, bproj);
}

// Round 2
// 209.902 us; speedup vs baseline: 5.7563x; 5.7563x over previous
//
#include <hip/hip_runtime.h>
#include <math.h>
#include <stdint.h>

namespace {

constexpr int Nseq = 1024;
constexpr int Dm = 768;
constexpr int threeD = 2304;
constexpr int Mrows = 8192;

using bf16x8 = __attribute__((ext_vector_type(8))) short;
using f32x4 = __attribute__((ext_vector_type(4))) float;
using us4 = __attribute__((ext_vector_type(4))) unsigned short;

__device__ __forceinline__ unsigned short f2bf(float f) {
  union { float f; uint32_t u; } v;
  v.f = f;
  uint32_t r = v.u + 0x7fffu + ((v.u >> 16) & 1u);
  return (unsigned short)(r >> 16);
}

__device__ __forceinline__ void gload_lds16(const void* g, void* l) {
  __builtin_amdgcn_global_load_lds(
      (const __attribute__((address_space(1))) unsigned int*)(uintptr_t)g,
      (__attribute__((address_space(3))) unsigned int*)(uintptr_t)l, 16, 0, 0);
}

// ---------------------------------------------------------------------------
// fp32 -> bf16 elementwise cast (vectorized 4/thread)
// ---------------------------------------------------------------------------
__global__ __launch_bounds__(256) void cast_f32_bf16(
    const float* __restrict__ in, unsigned short* __restrict__ outp, int n4) {
  int i = blockIdx.x * blockDim.x + threadIdx.x;
  if (i < n4) {
    float4 v = ((const float4*)in)[i];
    us4 u = {f2bf(v.x), f2bf(v.y), f2bf(v.z), f2bf(v.w)};
    ((us4*)outp)[i] = u;
  }
}

// ---------------------------------------------------------------------------
// W[K][N] fp32 -> Wt[N][K] bf16 (32x32 LDS tile transpose)
// ---------------------------------------------------------------------------
__global__ __launch_bounds__(256) void transpose_cast(
    const float* __restrict__ W, unsigned short* __restrict__ Wt, int K, int N) {
  __shared__ unsigned short tile[32][33];
  const int n0 = blockIdx.x * 32, k0 = blockIdx.y * 32;
  const int tx = threadIdx.x & 31, ty = threadIdx.x >> 5;
#pragma unroll
  for (int i = 0; i < 32; i += 8)
    tile[ty + i][tx] = f2bf(W[(size_t)(k0 + ty + i) * N + n0 + tx]);
  __syncthreads();
#pragma unroll
  for (int i = 0; i < 32; i += 8)
    Wt[(size_t)(n0 + ty + i) * K + k0 + tx] = tile[tx][ty + i];
}

// ---------------------------------------------------------------------------
// bf16 MFMA GEMM: C[M][N] = A[M][K] @ Bt[N][K]^T. 128x128 tile, BK=32,
// 4 waves (each 64x64 = 4x4 fragments of 16x16x32), global_load_lds staging.
// ---------------------------------------------------------------------------
template <bool BF16_OUT>
__global__ __launch_bounds__(256) void gemm_bf16(
    const unsigned short* __restrict__ A, const unsigned short* __restrict__ Bt,
    void* __restrict__ C, const float* __restrict__ bias, int Ndim, int K) {
  __shared__ unsigned short As[128 * 32];
  __shared__ unsigned short Bs[128 * 32];
  const int tid = threadIdx.x;
  const int wid = tid >> 6;
  const int lane = tid & 63;
  const int l15 = lane & 15, lg = lane >> 4;
  const int row0 = blockIdx.y * 128, col0 = blockIdx.x * 128;
  const int wr = (wid >> 1) * 64, wc = (wid & 1) * 64;
  const int lr = lane >> 2;       // row within 16-row chunk
  const int lk = (lane & 3) * 8;  // elem offset within 32-elem row
  f32x4 acc[4][4] = {};
  for (int k0 = 0; k0 < K; k0 += 32) {
    __syncthreads();
#pragma unroll
    for (int it = 0; it < 2; ++it) {
      const int c = wid * 2 + it;  // 16-row chunk index 0..7
      gload_lds16(&A[(size_t)(row0 + c * 16 + lr) * K + k0 + lk], &As[c * 512]);
      gload_lds16(&Bt[(size_t)(col0 + c * 16 + lr) * K + k0 + lk], &Bs[c * 512]);
    }
    __syncthreads();
    bf16x8 av[4], bv[4];
#pragma unroll
    for (int m = 0; m < 4; ++m)
      av[m] = *(const bf16x8*)&As[(wr + m * 16 + l15) * 32 + lg * 8];
#pragma unroll
    for (int n = 0; n < 4; ++n)
      bv[n] = *(const bf16x8*)&Bs[(wc + n * 16 + l15) * 32 + lg * 8];
#pragma unroll
    for (int m = 0; m < 4; ++m)
#pragma unroll
      for (int n = 0; n < 4; ++n)
        acc[m][n] =
            __builtin_amdgcn_mfma_f32_16x16x32_bf16(av[m], bv[n], acc[m][n], 0, 0, 0);
  }
#pragma unroll
  for (int m = 0; m < 4; ++m) {
#pragma unroll
    for (int n = 0; n < 4; ++n) {
      const int col = col0 + wc + n * 16 + l15;
#pragma unroll
      for (int rr = 0; rr < 4; ++rr) {
        const size_t idx = (size_t)(row0 + wr + m * 16 + lg * 4 + rr) * Ndim + col;
        if constexpr (BF16_OUT)
          ((unsigned short*)C)[idx] = f2bf(acc[m][n][rr]);
        else
          ((float*)C)[idx] = acc[m][n][rr] + bias[col];
      }
    }
  }
}

// ---------------------------------------------------------------------------
// MFMA flash attention. Block = (qt, h, b): 64 q-rows, 4 waves x 16 rows.
// KB=64 key tiles: K staged [key][d] (stride 72), V staged transposed [d][key].
// Online softmax in f32; P -> bf16 via per-wave LDS relayout.
// qkv bf16 [B*N][2304] (q|k|v each [H=12][64]); out bf16 [B*N][768].
// ---------------------------------------------------------------------------
__global__ __launch_bounds__(256) void attn_mfma(
    const unsigned short* __restrict__ qkv, unsigned short* __restrict__ outb) {
  constexpr int LV = 72;
  __shared__ unsigned short Ks[64 * LV];
  __shared__ unsigned short Vt[64 * LV];
  __shared__ unsigned short Pl[4 * 16 * LV];
  const int tid = threadIdx.x;
  const int wid = tid >> 6;
  const int lane = tid & 63;
  const int l15 = lane & 15, lg = lane >> 4;
  const int qt = blockIdx.x, h = blockIdx.y, b = blockIdx.z;
  const size_t rb = (size_t)b * Nseq;
  const int hoff = h * 64;
  bf16x8 qf[2];
  {
    const size_t qrow = rb + qt * 64 + wid * 16 + l15;
#pragma unroll
    for (int ks = 0; ks < 2; ++ks)
      qf[ks] = *(const bf16x8*)&qkv[qrow * threeD + hoff + ks * 32 + lg * 8];
  }
  float m_run[4], l_run[4];
  f32x4 o[4] = {};
#pragma unroll
  for (int rr = 0; rr < 4; ++rr) {
    m_run[rr] = -1e30f;
    l_run[rr] = 0.f;
  }
  for (int kt = 0; kt < Nseq / 64; ++kt) {
    __syncthreads();
#pragma unroll
    for (int it = 0; it < 2; ++it) {
      const int f = tid + it * 256;  // 0..511
      const int key = f >> 3;        // 0..63
      const int d0 = (f & 7) * 8;    // 0..56
      const size_t g = (rb + kt * 64 + key) * threeD + hoff + d0;
      bf16x8 kv = *(const bf16x8*)&qkv[g + Dm];
      *(bf16x8*)&Ks[key * LV + d0] = kv;
      bf16x8 vv = *(const bf16x8*)&qkv[g + 2 * Dm];
#pragma unroll
      for (int j = 0; j < 8; ++j)
        Vt[(d0 + j) * LV + key] = (unsigned short)vv[j];
    }
    __syncthreads();
    // S = Q K^T (f32 accum), rows (lg*4+rr), cols nf*16+l15
    f32x4 s[4] = {};
#pragma unroll
    for (int nf = 0; nf < 4; ++nf) {
#pragma unroll
      for (int ks = 0; ks < 2; ++ks) {
        bf16x8 kf = *(const bf16x8*)&Ks[(nf * 16 + l15) * LV + ks * 32 + lg * 8];
        s[nf] = __builtin_amdgcn_mfma_f32_16x16x32_bf16(qf[ks], kf, s[nf], 0, 0, 0);
      }
    }
    float al[4];
#pragma unroll
    for (int rr = 0; rr < 4; ++rr) {
#pragma unroll
      for (int nf = 0; nf < 4; ++nf) s[nf][rr] *= 0.125f;
      float m0 = fmaxf(fmaxf(s[0][rr], s[1][rr]), fmaxf(s[2][rr], s[3][rr]));
      m0 = fmaxf(m0, __shfl_xor(m0, 1));
      m0 = fmaxf(m0, __shfl_xor(m0, 2));
      m0 = fmaxf(m0, __shfl_xor(m0, 4));
      m0 = fmaxf(m0, __shfl_xor(m0, 8));
      const float mn = fmaxf(m_run[rr], m0);
      al[rr] = __expf(m_run[rr] - mn);
      m_run[rr] = mn;
      float pp = 0.f;
#pragma unroll
      for (int nf = 0; nf < 4; ++nf) {
        const float e = __expf(s[nf][rr] - mn);
        s[nf][rr] = e;
        pp += e;
      }
      pp += __shfl_xor(pp, 1);
      pp += __shfl_xor(pp, 2);
      pp += __shfl_xor(pp, 4);
      pp += __shfl_xor(pp, 8);
      l_run[rr] = l_run[rr] * al[rr] + pp;
    }
#pragma unroll
    for (int nf = 0; nf < 4; ++nf)
#pragma unroll
      for (int rr = 0; rr < 4; ++rr) o[nf][rr] *= al[rr];
    // P (D-layout) -> per-wave LDS -> A-layout fragments
#pragma unroll
    for (int nf = 0; nf < 4; ++nf)
#pragma unroll
      for (int rr = 0; rr < 4; ++rr)
        Pl[wid * (16 * LV) + (lg * 4 + rr) * LV + nf * 16 + l15] = f2bf(s[nf][rr]);
#pragma unroll
    for (int ks = 0; ks < 2; ++ks) {
      bf16x8 pa = *(const bf16x8*)&Pl[wid * (16 * LV) + l15 * LV + ks * 32 + lg * 8];
#pragma unroll
      for (int nf = 0; nf < 4; ++nf) {
        bf16x8 vf = *(const bf16x8*)&Vt[(nf * 16 + l15) * LV + ks * 32 + lg * 8];
        o[nf] = __builtin_amdgcn_mfma_f32_16x16x32_bf16(pa, vf, o[nf], 0, 0, 0);
      }
    }
  }
  const size_t orow = rb + qt * 64 + wid * 16;
#pragma unroll
  for (int rr = 0; rr < 4; ++rr) {
    const float inv = 1.f / l_run[rr];
#pragma unroll
    for (int nf = 0; nf < 4; ++nf)
      outb[(orow + lg * 4 + rr) * Dm + hoff + nf * 16 + l15] = f2bf(o[nf][rr] * inv);
  }
}

}  // namespace

extern "C" void kernel_launch(void* const* d_in, const int* in_sizes, int n_in,
                              void* d_out, int out_size, void* d_ws,
                              size_t ws_size, hipStream_t stream) {
  (void)in_sizes;
  (void)n_in;
  (void)out_size;
  (void)ws_size;
  const float* x = (const float*)d_in[0];      // [8192][768]
  const float* Wqkv = (const float*)d_in[1];   // [768][2304]
  const float* Wproj = (const float*)d_in[2];  // [768][768]
  const float* bproj = (const float*)d_in[3];  // [768]
  float* out = (float*)d_out;                  // [8192][768]

  char* w = (char*)d_ws;
  unsigned short* xb = (unsigned short*)w;                   // 12.58 MB
  w += (size_t)Mrows * Dm * 2;
  unsigned short* wqkvt = (unsigned short*)w;                // 3.54 MB
  w += (size_t)threeD * Dm * 2;
  unsigned short* wprojt = (unsigned short*)w;               // 1.18 MB
  w += (size_t)Dm * Dm * 2;
  unsigned short* qkvb = (unsigned short*)w;                 // 37.75 MB
  w += (size_t)Mrows * threeD * 2;
  unsigned short* attnb = (unsigned short*)w;                // 12.58 MB

  cast_f32_bf16<<<(Mrows * Dm / 4 + 255) / 256, 256, 0, stream>>>(x, xb,
                                                                  Mrows * Dm / 4);
  transpose_cast<<<dim3(threeD / 32, Dm / 32), 256, 0, stream>>>(Wqkv, wqkvt, Dm,
                                                                 threeD);
  transpose_cast<<<dim3(Dm / 32, Dm / 32), 256, 0, stream>>>(Wproj, wprojt, Dm, Dm);
  // qkv = x @ Wqkv (bf16 out)
  gemm_bf16<true><<<dim3(threeD / 128, Mrows / 128), 256, 0, stream>>>(
      xb, wqkvt, qkvb, nullptr, threeD, Dm);
  // flash attention
  attn_mfma<<<dim3(Nseq / 64, 12, 8), 256, 0, stream>>>(qkvb, attnb);
  // out = attn @ Wproj + bias (f32 out)
  gemm_bf16<false><<<dim3(Dm / 128, Mrows / 128), 256, 0, stream>>>(
      attnb, wprojt, out, bproj, Dm, Dm);
}

// Round 3
// 182.391 us; speedup vs baseline: 6.6245x; 1.1508x over previous
//
#include <hip/hip_runtime.h>
#include <math.h>
#include <stdint.h>

namespace {

constexpr int Nseq = 1024;
constexpr int Dm = 768;
constexpr int threeD = 2304;
constexpr int Mrows = 8192;
constexpr int Hh = 12;
// scale (1/8) * log2(e)
constexpr float kScaleLog2 = 0.18033688011112042f;

using bf16x8 = __attribute__((ext_vector_type(8))) short;
using f32x4 = __attribute__((ext_vector_type(4))) float;
using us4 = __attribute__((ext_vector_type(4))) unsigned short;

__device__ __forceinline__ unsigned short f2bf(float f) {
  union { float f; uint32_t u; } v;
  v.f = f;
  uint32_t r = v.u + 0x7fffu + ((v.u >> 16) & 1u);
  return (unsigned short)(r >> 16);
}

__device__ __forceinline__ void gload_lds16(const void* g, void* l) {
  __builtin_amdgcn_global_load_lds(
      (const __attribute__((address_space(1))) unsigned int*)(uintptr_t)g,
      (__attribute__((address_space(3))) unsigned int*)(uintptr_t)l, 16, 0, 0);
}

// ---------------------------------------------------------------------------
// fp32 -> bf16 elementwise cast (vectorized 4/thread)
// ---------------------------------------------------------------------------
__global__ __launch_bounds__(256) void cast_f32_bf16(
    const float* __restrict__ in, unsigned short* __restrict__ outp, int n4) {
  int i = blockIdx.x * blockDim.x + threadIdx.x;
  if (i < n4) {
    float4 v = ((const float4*)in)[i];
    us4 u = {f2bf(v.x), f2bf(v.y), f2bf(v.z), f2bf(v.w)};
    ((us4*)outp)[i] = u;
  }
}

// ---------------------------------------------------------------------------
// W[K][N] fp32 -> Wt[N][K] bf16 (32x32 LDS tile transpose)
// ---------------------------------------------------------------------------
__global__ __launch_bounds__(256) void transpose_cast(
    const float* __restrict__ W, unsigned short* __restrict__ Wt, int K, int N) {
  __shared__ unsigned short tile[32][33];
  const int n0 = blockIdx.x * 32, k0 = blockIdx.y * 32;
  const int tx = threadIdx.x & 31, ty = threadIdx.x >> 5;
#pragma unroll
  for (int i = 0; i < 32; i += 8)
    tile[ty + i][tx] = f2bf(W[(size_t)(k0 + ty + i) * N + n0 + tx]);
  __syncthreads();
#pragma unroll
  for (int i = 0; i < 32; i += 8)
    Wt[(size_t)(n0 + ty + i) * K + k0 + tx] = tile[tx][ty + i];
}

// ---------------------------------------------------------------------------
// bf16 MFMA GEMM: C = A[M][K] @ Bt[N][K]^T. 128x128 tile, BK=32, 4 waves.
// MODE 0 (QKV): cols <1536 -> qk buffer [M][1536] bf16; cols >=1536 -> V
//   transposed to vtb[(b*12+h)*64+d][1024] bf16 (packed 4-token stores).
// MODE 1 (proj): f32 out [M][768] + bias.
// ---------------------------------------------------------------------------
template <int MODE>
__global__ __launch_bounds__(256) void gemm_bf16(
    const unsigned short* __restrict__ A, const unsigned short* __restrict__ Bt,
    void* __restrict__ C0, void* __restrict__ C1,
    const float* __restrict__ bias, int K) {
  __shared__ unsigned short As[128 * 32];
  __shared__ unsigned short Bs[128 * 32];
  const int tid = threadIdx.x;
  const int wid = tid >> 6;
  const int lane = tid & 63;
  const int l15 = lane & 15, lg = lane >> 4;
  const int row0 = blockIdx.y * 128, col0 = blockIdx.x * 128;
  const int wr = (wid >> 1) * 64, wc = (wid & 1) * 64;
  const int lr = lane >> 2;
  const int lk = (lane & 3) * 8;
  f32x4 acc[4][4] = {};
  for (int k0 = 0; k0 < K; k0 += 32) {
    __syncthreads();
#pragma unroll
    for (int it = 0; it < 2; ++it) {
      const int c = wid * 2 + it;
      gload_lds16(&A[(size_t)(row0 + c * 16 + lr) * K + k0 + lk], &As[c * 512]);
      gload_lds16(&Bt[(size_t)(col0 + c * 16 + lr) * K + k0 + lk], &Bs[c * 512]);
    }
    __syncthreads();
    bf16x8 av[4], bv[4];
#pragma unroll
    for (int m = 0; m < 4; ++m)
      av[m] = *(const bf16x8*)&As[(wr + m * 16 + l15) * 32 + lg * 8];
#pragma unroll
    for (int n = 0; n < 4; ++n)
      bv[n] = *(const bf16x8*)&Bs[(wc + n * 16 + l15) * 32 + lg * 8];
#pragma unroll
    for (int m = 0; m < 4; ++m)
#pragma unroll
      for (int n = 0; n < 4; ++n)
        acc[m][n] =
            __builtin_amdgcn_mfma_f32_16x16x32_bf16(av[m], bv[n], acc[m][n], 0, 0, 0);
  }
  if constexpr (MODE == 1) {
#pragma unroll
    for (int m = 0; m < 4; ++m)
#pragma unroll
      for (int n = 0; n < 4; ++n) {
        const int col = col0 + wc + n * 16 + l15;
#pragma unroll
        for (int rr = 0; rr < 4; ++rr)
          ((float*)C0)[(size_t)(row0 + wr + m * 16 + lg * 4 + rr) * Dm + col] =
              acc[m][n][rr] + bias[col];
      }
  } else if (col0 < 1536) {  // Q/K -> qk buffer, stride 1536
#pragma unroll
    for (int m = 0; m < 4; ++m)
#pragma unroll
      for (int n = 0; n < 4; ++n) {
        const int col = col0 + wc + n * 16 + l15;
#pragma unroll
        for (int rr = 0; rr < 4; ++rr)
          ((unsigned short*)C0)[(size_t)(row0 + wr + m * 16 + lg * 4 + rr) * 1536 +
                                col] = f2bf(acc[m][n][rr]);
      }
  } else {  // V -> vtb[(b*12+h)*64+d][1024], 4 consecutive tokens per store
#pragma unroll
    for (int m = 0; m < 4; ++m)
#pragma unroll
      for (int n = 0; n < 4; ++n) {
        const int c = col0 + wc + n * 16 + l15 - 1536;  // h*64+d
        const int row = row0 + wr + m * 16 + lg * 4;    // first of 4 tokens
        const int bb = row >> 10, n0 = row & 1023;
        us4 pk = {f2bf(acc[m][n][0]), f2bf(acc[m][n][1]), f2bf(acc[m][n][2]),
                  f2bf(acc[m][n][3])};
        *(us4*)&((unsigned short*)C1)[((size_t)bb * 768 + c) * 1024 + n0] = pk;
      }
  }
}

// ---------------------------------------------------------------------------
// MFMA flash attention. Block = (qt, h, b): 64 q-rows, 4 waves x 16 rows.
// K staged [key][d] from qkb; V staged [d][key] directly from pre-transposed
// vtb (vectorized). Next tile's K/V prefetched to registers under compute.
// ---------------------------------------------------------------------------
__global__ __launch_bounds__(256) void attn_mfma(
    const unsigned short* __restrict__ qkb, const unsigned short* __restrict__ vtb,
    unsigned short* __restrict__ outb) {
  constexpr int LV = 72;
  __shared__ unsigned short Ks[64 * LV];
  __shared__ unsigned short Vs[64 * LV];
  __shared__ unsigned short Pl[4 * 16 * LV];
  const int tid = threadIdx.x;
  const int wid = tid >> 6;
  const int lane = tid & 63;
  const int l15 = lane & 15, lg = lane >> 4;
  const int qt = blockIdx.x, h = blockIdx.y, b = blockIdx.z;
  const size_t rb = (size_t)b * Nseq;
  const int hoff = h * 64;
  const size_t vbase = ((size_t)b * 768 + hoff) * 1024;  // vtb row (b*12+h)*64
  bf16x8 qf[2];
  {
    const size_t qrow = rb + qt * 64 + wid * 16 + l15;
#pragma unroll
    for (int ks = 0; ks < 2; ++ks)
      qf[ks] = *(const bf16x8*)&qkb[qrow * 1536 + hoff + ks * 32 + lg * 8];
  }
  // staging assignment: two chunks per thread for each of K and V
  const int r0 = tid >> 3, o0 = (tid & 7) * 8;            // chunk c0 = tid
  const int r1 = (tid + 256) >> 3, o1 = o0;               // chunk c1 = tid+256
  bf16x8 kreg0, kreg1, vreg0, vreg1;
  auto loadt = [&](int kt) {
    const size_t kb = (rb + kt * 64) * 1536 + 768 + hoff;
    kreg0 = *(const bf16x8*)&qkb[kb + (size_t)r0 * 1536 + o0];
    kreg1 = *(const bf16x8*)&qkb[kb + (size_t)r1 * 1536 + o1];
    vreg0 = *(const bf16x8*)&vtb[vbase + (size_t)r0 * 1024 + kt * 64 + o0];
    vreg1 = *(const bf16x8*)&vtb[vbase + (size_t)r1 * 1024 + kt * 64 + o1];
  };
  loadt(0);
  float m_run[4], l_run[4];
  f32x4 o[4] = {};
#pragma unroll
  for (int rr = 0; rr < 4; ++rr) {
    m_run[rr] = -1e30f;
    l_run[rr] = 0.f;
  }
  for (int kt = 0; kt < Nseq / 64; ++kt) {
    __syncthreads();  // prior tile fully consumed
    *(bf16x8*)&Ks[r0 * LV + o0] = kreg0;
    *(bf16x8*)&Ks[r1 * LV + o1] = kreg1;
    *(bf16x8*)&Vs[r0 * LV + o0] = vreg0;
    *(bf16x8*)&Vs[r1 * LV + o1] = vreg1;
    __syncthreads();  // staging visible
    if (kt + 1 < Nseq / 64) loadt(kt + 1);  // prefetch under compute
    // S = Q K^T, rows lg*4+rr, cols nf*16+l15
    f32x4 s[4] = {};
#pragma unroll
    for (int nf = 0; nf < 4; ++nf)
#pragma unroll
      for (int ks = 0; ks < 2; ++ks) {
        bf16x8 kf = *(const bf16x8*)&Ks[(nf * 16 + l15) * LV + ks * 32 + lg * 8];
        s[nf] = __builtin_amdgcn_mfma_f32_16x16x32_bf16(qf[ks], kf, s[nf], 0, 0, 0);
      }
    float al[4];
#pragma unroll
    for (int rr = 0; rr < 4; ++rr) {
#pragma unroll
      for (int nf = 0; nf < 4; ++nf) s[nf][rr] *= kScaleLog2;
      float m0 = fmaxf(fmaxf(s[0][rr], s[1][rr]), fmaxf(s[2][rr], s[3][rr]));
      m0 = fmaxf(m0, __shfl_xor(m0, 1));
      m0 = fmaxf(m0, __shfl_xor(m0, 2));
      m0 = fmaxf(m0, __shfl_xor(m0, 4));
      m0 = fmaxf(m0, __shfl_xor(m0, 8));
      const float mn = fmaxf(m_run[rr], m0);
      al[rr] = exp2f(m_run[rr] - mn);
      m_run[rr] = mn;
      float pp = 0.f;
#pragma unroll
      for (int nf = 0; nf < 4; ++nf) {
        const float e = exp2f(s[nf][rr] - mn);
        s[nf][rr] = e;
        pp += e;
      }
      pp += __shfl_xor(pp, 1);
      pp += __shfl_xor(pp, 2);
      pp += __shfl_xor(pp, 4);
      pp += __shfl_xor(pp, 8);
      l_run[rr] = l_run[rr] * al[rr] + pp;
    }
#pragma unroll
    for (int nf = 0; nf < 4; ++nf)
#pragma unroll
      for (int rr = 0; rr < 4; ++rr) o[nf][rr] *= al[rr];
    // P (D-layout) -> per-wave LDS -> A-layout fragments (no barrier needed)
#pragma unroll
    for (int nf = 0; nf < 4; ++nf)
#pragma unroll
      for (int rr = 0; rr < 4; ++rr)
        Pl[wid * (16 * LV) + (lg * 4 + rr) * LV + nf * 16 + l15] = f2bf(s[nf][rr]);
#pragma unroll
    for (int ks = 0; ks < 2; ++ks) {
      bf16x8 pa = *(const bf16x8*)&Pl[wid * (16 * LV) + l15 * LV + ks * 32 + lg * 8];
#pragma unroll
      for (int nf = 0; nf < 4; ++nf) {
        bf16x8 vf = *(const bf16x8*)&Vs[(nf * 16 + l15) * LV + ks * 32 + lg * 8];
        o[nf] = __builtin_amdgcn_mfma_f32_16x16x32_bf16(pa, vf, o[nf], 0, 0, 0);
      }
    }
  }
  const size_t orow = rb + qt * 64 + wid * 16;
#pragma unroll
  for (int rr = 0; rr < 4; ++rr) {
    const float inv = 1.f / l_run[rr];
#pragma unroll
    for (int nf = 0; nf < 4; ++nf)
      outb[(orow + lg * 4 + rr) * Dm + hoff + nf * 16 + l15] = f2bf(o[nf][rr] * inv);
  }
}

}  // namespace

extern "C" void kernel_launch(void* const* d_in, const int* in_sizes, int n_in,
                              void* d_out, int out_size, void* d_ws,
                              size_t ws_size, hipStream_t stream) {
  (void)in_sizes;
  (void)n_in;
  (void)out_size;
  (void)ws_size;
  const float* x = (const float*)d_in[0];      // [8192][768]
  const float* Wqkv = (const float*)d_in[1];   // [768][2304]
  const float* Wproj = (const float*)d_in[2];  // [768][768]
  const float* bproj = (const float*)d_in[3];  // [768]
  float* out = (float*)d_out;                  // [8192][768]

  char* w = (char*)d_ws;
  unsigned short* xb = (unsigned short*)w;      // 12.58 MB
  w += (size_t)Mrows * Dm * 2;
  unsigned short* wqkvt = (unsigned short*)w;   // 3.54 MB
  w += (size_t)threeD * Dm * 2;
  unsigned short* wprojt = (unsigned short*)w;  // 1.18 MB
  w += (size_t)Dm * Dm * 2;
  unsigned short* qkb = (unsigned short*)w;     // [8192][1536] 25.17 MB
  w += (size_t)Mrows * 1536 * 2;
  unsigned short* vtb = (unsigned short*)w;     // [96*64][1024] 12.58 MB
  w += (size_t)96 * 64 * 1024 * 2;
  unsigned short* attnb = (unsigned short*)w;   // 12.58 MB

  cast_f32_bf16<<<(Mrows * Dm / 4 + 255) / 256, 256, 0, stream>>>(
      x, xb, Mrows * Dm / 4);
  transpose_cast<<<dim3(threeD / 32, Dm / 32), 256, 0, stream>>>(
      Wqkv, wqkvt, Dm, threeD);
  transpose_cast<<<dim3(Dm / 32, Dm / 32), 256, 0, stream>>>(Wproj, wprojt, Dm, Dm);
  // qkv = x @ Wqkv; Q/K -> qkb, V -> vtb (transposed)
  gemm_bf16<0><<<dim3(threeD / 128, Mrows / 128), 256, 0, stream>>>(
      xb, wqkvt, qkb, vtb, nullptr, Dm);
  // flash attention
  attn_mfma<<<dim3(Nseq / 64, Hh, 8), 256, 0, stream>>>(qkb, vtb, attnb);
  // out = attn @ Wproj + bias (f32 out)
  gemm_bf16<1><<<dim3(Dm / 128, Mrows / 128), 256, 0, stream>>>(
      attnb, wprojt, out, nullptr, bproj, Dm);
}

// Round 4
// 147.176 us; speedup vs baseline: 8.2096x; 1.2393x over previous
//
#include <hip/hip_runtime.h>
#include <math.h>
#include <stdint.h>

namespace {

constexpr int Nseq = 1024;
constexpr int Dm = 768;
constexpr int threeD = 2304;
constexpr int Mrows = 8192;
constexpr int Hh = 12;
// scale (1/8) * log2(e)
constexpr float kScaleLog2 = 0.18033688011112042f;

using bf16x8 = __attribute__((ext_vector_type(8))) short;
using f32x4 = __attribute__((ext_vector_type(4))) float;
using f32x16 = __attribute__((ext_vector_type(16))) float;
using us4 = __attribute__((ext_vector_type(4))) unsigned short;

__device__ __forceinline__ unsigned short f2bf(float f) {
  union { float f; uint32_t u; } v;
  v.f = f;
  uint32_t r = v.u + 0x7fffu + ((v.u >> 16) & 1u);
  return (unsigned short)(r >> 16);
}

__device__ __forceinline__ uint32_t cvtpk_bf16(float lo, float hi) {
  uint32_t r;
  asm("v_cvt_pk_bf16_f32 %0, %1, %2" : "=v"(r) : "v"(lo), "v"(hi));
  return r;
}

__device__ __forceinline__ void gload_lds16(const void* g, void* l) {
  __builtin_amdgcn_global_load_lds(
      (const __attribute__((address_space(1))) unsigned int*)(uintptr_t)g,
      (__attribute__((address_space(3))) unsigned int*)(uintptr_t)l, 16, 0, 0);
}

// ---------------------------------------------------------------------------
// fp32 -> bf16 elementwise cast (vectorized 4/thread)
// ---------------------------------------------------------------------------
__global__ __launch_bounds__(256) void cast_f32_bf16(
    const float* __restrict__ in, unsigned short* __restrict__ outp, int n4) {
  int i = blockIdx.x * blockDim.x + threadIdx.x;
  if (i < n4) {
    float4 v = ((const float4*)in)[i];
    us4 u = {f2bf(v.x), f2bf(v.y), f2bf(v.z), f2bf(v.w)};
    ((us4*)outp)[i] = u;
  }
}

// ---------------------------------------------------------------------------
// W[K][N] fp32 -> Wt[N][K] bf16 (32x32 LDS tile transpose)
// ---------------------------------------------------------------------------
__global__ __launch_bounds__(256) void transpose_cast(
    const float* __restrict__ W, unsigned short* __restrict__ Wt, int K, int N) {
  __shared__ unsigned short tile[32][33];
  const int n0 = blockIdx.x * 32, k0 = blockIdx.y * 32;
  const int tx = threadIdx.x & 31, ty = threadIdx.x >> 5;
#pragma unroll
  for (int i = 0; i < 32; i += 8)
    tile[ty + i][tx] = f2bf(W[(size_t)(k0 + ty + i) * N + n0 + tx]);
  __syncthreads();
#pragma unroll
  for (int i = 0; i < 32; i += 8)
    Wt[(size_t)(n0 + ty + i) * K + k0 + tx] = tile[tx][ty + i];
}

// ---------------------------------------------------------------------------
// bf16 MFMA GEMM: C = A[M][K] @ Bt[N][K]^T. 128x128 tile, BK=32, 4 waves.
// MODE 0 (QKV): cols <1536 -> qk buffer [M][1536] bf16; cols >=1536 -> V
//   transposed to vtb[(b*12+h)*64+d][1024] bf16 (packed 4-token stores).
// MODE 1 (proj): f32 out [M][768] + bias.
// ---------------------------------------------------------------------------
template <int MODE>
__global__ __launch_bounds__(256) void gemm_bf16(
    const unsigned short* __restrict__ A, const unsigned short* __restrict__ Bt,
    void* __restrict__ C0, void* __restrict__ C1,
    const float* __restrict__ bias, int K) {
  __shared__ unsigned short As[128 * 32];
  __shared__ unsigned short Bs[128 * 32];
  const int tid = threadIdx.x;
  const int wid = tid >> 6;
  const int lane = tid & 63;
  const int l15 = lane & 15, lg = lane >> 4;
  const int row0 = blockIdx.y * 128, col0 = blockIdx.x * 128;
  const int wr = (wid >> 1) * 64, wc = (wid & 1) * 64;
  const int lr = lane >> 2;
  const int lk = (lane & 3) * 8;
  f32x4 acc[4][4] = {};
  for (int k0 = 0; k0 < K; k0 += 32) {
    __syncthreads();
#pragma unroll
    for (int it = 0; it < 2; ++it) {
      const int c = wid * 2 + it;
      gload_lds16(&A[(size_t)(row0 + c * 16 + lr) * K + k0 + lk], &As[c * 512]);
      gload_lds16(&Bt[(size_t)(col0 + c * 16 + lr) * K + k0 + lk], &Bs[c * 512]);
    }
    __syncthreads();
    bf16x8 av[4], bv[4];
#pragma unroll
    for (int m = 0; m < 4; ++m)
      av[m] = *(const bf16x8*)&As[(wr + m * 16 + l15) * 32 + lg * 8];
#pragma unroll
    for (int n = 0; n < 4; ++n)
      bv[n] = *(const bf16x8*)&Bs[(wc + n * 16 + l15) * 32 + lg * 8];
#pragma unroll
    for (int m = 0; m < 4; ++m)
#pragma unroll
      for (int n = 0; n < 4; ++n)
        acc[m][n] =
            __builtin_amdgcn_mfma_f32_16x16x32_bf16(av[m], bv[n], acc[m][n], 0, 0, 0);
  }
  if constexpr (MODE == 1) {
#pragma unroll
    for (int m = 0; m < 4; ++m)
#pragma unroll
      for (int n = 0; n < 4; ++n) {
        const int col = col0 + wc + n * 16 + l15;
#pragma unroll
        for (int rr = 0; rr < 4; ++rr)
          ((float*)C0)[(size_t)(row0 + wr + m * 16 + lg * 4 + rr) * Dm + col] =
              acc[m][n][rr] + bias[col];
      }
  } else if (col0 < 1536) {  // Q/K -> qk buffer, stride 1536
#pragma unroll
    for (int m = 0; m < 4; ++m)
#pragma unroll
      for (int n = 0; n < 4; ++n) {
        const int col = col0 + wc + n * 16 + l15;
#pragma unroll
        for (int rr = 0; rr < 4; ++rr)
          ((unsigned short*)C0)[(size_t)(row0 + wr + m * 16 + lg * 4 + rr) * 1536 +
                                col] = f2bf(acc[m][n][rr]);
      }
  } else {  // V -> vtb[(b*12+h)*64+d][1024], 4 consecutive tokens per store
#pragma unroll
    for (int m = 0; m < 4; ++m)
#pragma unroll
      for (int n = 0; n < 4; ++n) {
        const int c = col0 + wc + n * 16 + l15 - 1536;  // h*64+d
        const int row = row0 + wr + m * 16 + lg * 4;    // first of 4 tokens
        const int bb = row >> 10, n0 = row & 1023;
        us4 pk = {f2bf(acc[m][n][0]), f2bf(acc[m][n][1]), f2bf(acc[m][n][2]),
                  f2bf(acc[m][n][3])};
        *(us4*)&((unsigned short*)C1)[((size_t)bb * 768 + c) * 1024 + n0] = pk;
      }
  }
}

// ---------------------------------------------------------------------------
// MFMA flash attention, swapped-operand (T12) structure.
// Block = (qt, h, b): 128 q-rows, 4 waves x 32 rows. Per 64-key tile:
//   S^T[key][q] = mfma_32x32x16(Kfrag, Qfrag): lane owns q-row = lane&31,
//     32 scores in regs (keys with bit2==lane>>5), partner lane^32 has rest.
//   Softmax fully in-register (shfl_xor(,32) combines halves); defer-max.
//   P -> bf16 via v_cvt_pk_bf16_f32 + v_permlane32_swap_b32.
//   O^T[d][q] = mfma(Vtfrag, Pfrag): output col = own q-row -> lane-local
//     rescale and normalize.
// K and Vt staged double-buffered via global_load_lds with pre-swizzled
// source (chunk ^= row&7); reads use matching swizzle -> conflict-free.
// ---------------------------------------------------------------------------
__global__ __launch_bounds__(256) void attn_mfma(
    const unsigned short* __restrict__ qkb, const unsigned short* __restrict__ vtb,
    unsigned short* __restrict__ outb) {
  __shared__ unsigned short Ks[2][64 * 64];
  __shared__ unsigned short Vs[2][64 * 64];
  const int tid = threadIdx.x;
  const int wid = tid >> 6, lane = tid & 63;
  const int l31 = lane & 31, hi = lane >> 5;
  const int qt = blockIdx.x, h = blockIdx.y, b = blockIdx.z;
  const size_t rb = (size_t)b * Nseq;
  const int hoff = h * 64;
  const size_t vbase = ((size_t)b * 768 + hoff) * 1024;

  const int qrow = qt * 128 + wid * 32 + l31;
  bf16x8 Qf[4];
#pragma unroll
  for (int ks = 0; ks < 4; ++ks)
    Qf[ks] = *(const bf16x8*)&qkb[(rb + qrow) * 1536 + hoff + ks * 16 + hi * 8];

  // per-lane staging coords: 2 issues/buffer, 8 chunks (16B) per row
  int strow[2], scol[2];
#pragma unroll
  for (int it = 0; it < 2; ++it) {
    const int ci = it * 256 + wid * 64 + lane;
    const int tr = ci >> 3, cc = ci & 7;
    strow[it] = tr;
    scol[it] = (cc ^ (tr & 7)) * 8;  // pre-swizzled source chunk (shorts)
  }

  auto stage = [&](int kt, int bufi) {
#pragma unroll
    for (int it = 0; it < 2; ++it) {
      const int ldsoff = (it * 256 + wid * 64) * 8;
      gload_lds16(&qkb[(rb + kt * 64 + strow[it]) * 1536 + 768 + hoff + scol[it]],
                  &Ks[bufi][ldsoff]);
      gload_lds16(&vtb[vbase + (size_t)strow[it] * 1024 + kt * 64 + scol[it]],
                  &Vs[bufi][ldsoff]);
    }
  };

  float m_run = -3.0e38f, l_run = 0.f;
  f32x16 o0 = {}, o1 = {};

  stage(0, 0);
  __syncthreads();

  for (int kt = 0; kt < Nseq / 64; ++kt) {
    const int bufi = kt & 1;
    if (kt + 1 < Nseq / 64) stage(kt + 1, bufi ^ 1);
    const unsigned short* ksb = Ks[bufi];
    const unsigned short* vsb = Vs[bufi];
    // S^T = K . Q^T  (2 key-blocks of 32)
    f32x16 s0 = {}, s1 = {};
#pragma unroll
    for (int ks = 0; ks < 4; ++ks) {
      const int c = 2 * ks + hi;
      {
        const int tr = l31;
        bf16x8 kf = *(const bf16x8*)&ksb[tr * 64 + ((c ^ (tr & 7)) * 8)];
        s0 = __builtin_amdgcn_mfma_f32_32x32x16_bf16(kf, Qf[ks], s0, 0, 0, 0);
      }
      {
        const int tr = l31 + 32;
        bf16x8 kf = *(const bf16x8*)&ksb[tr * 64 + ((c ^ (tr & 7)) * 8)];
        s1 = __builtin_amdgcn_mfma_f32_32x32x16_bf16(kf, Qf[ks], s1, 0, 0, 0);
      }
    }
    // row max over own 32 + partner half (raw domain)
    float mx = s0[0];
#pragma unroll
    for (int i = 1; i < 16; ++i) mx = fmaxf(mx, s0[i]);
#pragma unroll
    for (int i = 0; i < 16; ++i) mx = fmaxf(mx, s1[i]);
    mx = fmaxf(mx, __shfl_xor(mx, 32));
    const float mn = fmaxf(m_run, mx);
    if (!__all((mn - m_run) * kScaleLog2 <= 8.f)) {  // defer-max (T13)
      const float al = exp2f((m_run - mn) * kScaleLog2);
#pragma unroll
      for (int i = 0; i < 16; ++i) {
        o0[i] *= al;
        o1[i] *= al;
      }
      l_run *= al;
      m_run = mn;
    }
    const float negmc = -m_run * kScaleLog2;
    float ps = 0.f;
#pragma unroll
    for (int i = 0; i < 16; ++i) {
      const float e0 = exp2f(fmaf(s0[i], kScaleLog2, negmc));
      const float e1 = exp2f(fmaf(s1[i], kScaleLog2, negmc));
      s0[i] = e0;
      s1[i] = e1;
      ps += e0 + e1;
    }
    ps += __shfl_xor(ps, 32);
    l_run += ps;
    // pack P into A/B-frag bf16 layout: 16 cvt_pk + 8 permlane32_swap
    bf16x8 Pf[4];
#pragma unroll
    for (int ks = 0; ks < 4; ++ks) {
      const f32x16 sv = (ks >> 1) ? s1 : s0;
      const int e0 = 8 * (ks & 1);
      uint32_t pe01 = cvtpk_bf16(sv[e0 + 0], sv[e0 + 1]);
      uint32_t pe23 = cvtpk_bf16(sv[e0 + 2], sv[e0 + 3]);
      uint32_t po01 = cvtpk_bf16(sv[e0 + 4], sv[e0 + 5]);
      uint32_t po23 = cvtpk_bf16(sv[e0 + 6], sv[e0 + 7]);
      asm("v_permlane32_swap_b32 %0, %1" : "+v"(pe01), "+v"(po01));
      asm("v_permlane32_swap_b32 %0, %1" : "+v"(pe23), "+v"(po23));
      union {
        uint32_t w[4];
        bf16x8 v;
      } u;
      u.w[0] = pe01;  // keys 16ks+{0,1}
      u.w[1] = pe23;  // keys 16ks+{2,3}
      u.w[2] = po01;  // keys 16ks+{4,5}
      u.w[3] = po23;  // keys 16ks+{6,7}
      Pf[ks] = u.v;
    }
    // O^T += V^T . P^T  (2 d-blocks of 32)
#pragma unroll
    for (int ks = 0; ks < 4; ++ks) {
      const int c = 2 * ks + hi;
      {
        const int tr = l31;
        bf16x8 vf = *(const bf16x8*)&vsb[tr * 64 + ((c ^ (tr & 7)) * 8)];
        o0 = __builtin_amdgcn_mfma_f32_32x32x16_bf16(vf, Pf[ks], o0, 0, 0, 0);
      }
      {
        const int tr = l31 + 32;
        bf16x8 vf = *(const bf16x8*)&vsb[tr * 64 + ((c ^ (tr & 7)) * 8)];
        o1 = __builtin_amdgcn_mfma_f32_32x32x16_bf16(vf, Pf[ks], o1, 0, 0, 0);
      }
    }
    __syncthreads();
  }
  // epilogue: lane owns q-row; d = (reg&3) + 8*(reg>>2) + 4*hi (+32 for o1)
  const float linv = 1.f / l_run;
  const size_t obase = (size_t)(rb + qrow) * Dm + hoff;
#pragma unroll
  for (int g = 0; g < 4; ++g) {
    us4 a = {f2bf(o0[g * 4 + 0] * linv), f2bf(o0[g * 4 + 1] * linv),
             f2bf(o0[g * 4 + 2] * linv), f2bf(o0[g * 4 + 3] * linv)};
    *(us4*)&outb[obase + g * 8 + hi * 4] = a;
    us4 bq = {f2bf(o1[g * 4 + 0] * linv), f2bf(o1[g * 4 + 1] * linv),
              f2bf(o1[g * 4 + 2] * linv), f2bf(o1[g * 4 + 3] * linv)};
    *(us4*)&outb[obase + 32 + g * 8 + hi * 4] = bq;
  }
}

}  // namespace

extern "C" void kernel_launch(void* const* d_in, const int* in_sizes, int n_in,
                              void* d_out, int out_size, void* d_ws,
                              size_t ws_size, hipStream_t stream) {
  (void)in_sizes;
  (void)n_in;
  (void)out_size;
  (void)ws_size;
  const float* x = (const float*)d_in[0];      // [8192][768]
  const float* Wqkv = (const float*)d_in[1];   // [768][2304]
  const float* Wproj = (const float*)d_in[2];  // [768][768]
  const float* bproj = (const float*)d_in[3];  // [768]
  float* out = (float*)d_out;                  // [8192][768]

  char* w = (char*)d_ws;
  unsigned short* xb = (unsigned short*)w;      // 12.58 MB
  w += (size_t)Mrows * Dm * 2;
  unsigned short* wqkvt = (unsigned short*)w;   // 3.54 MB
  w += (size_t)threeD * Dm * 2;
  unsigned short* wprojt = (unsigned short*)w;  // 1.18 MB
  w += (size_t)Dm * Dm * 2;
  unsigned short* qkb = (unsigned short*)w;     // [8192][1536] 25.17 MB
  w += (size_t)Mrows * 1536 * 2;
  unsigned short* vtb = (unsigned short*)w;     // [96*64][1024] 12.58 MB
  w += (size_t)96 * 64 * 1024 * 2;
  unsigned short* attnb = (unsigned short*)w;   // 12.58 MB

  cast_f32_bf16<<<(Mrows * Dm / 4 + 255) / 256, 256, 0, stream>>>(
      x, xb, Mrows * Dm / 4);
  transpose_cast<<<dim3(threeD / 32, Dm / 32), 256, 0, stream>>>(
      Wqkv, wqkvt, Dm, threeD);
  transpose_cast<<<dim3(Dm / 32, Dm / 32), 256, 0, stream>>>(Wproj, wprojt, Dm, Dm);
  // qkv = x @ Wqkv; Q/K -> qkb, V -> vtb (transposed)
  gemm_bf16<0><<<dim3(threeD / 128, Mrows / 128), 256, 0, stream>>>(
      xb, wqkvt, qkb, vtb, nullptr, Dm);
  // flash attention (128 q-rows per block)
  attn_mfma<<<dim3(Nseq / 128, Hh, 8), 256, 0, stream>>>(qkb, vtb, attnb);
  // out = attn @ Wproj + bias (f32 out)
  gemm_bf16<1><<<dim3(Dm / 128, Mrows / 128), 256, 0, stream>>>(
      attnb, wprojt, out, nullptr, bproj, Dm);
}

// Round 5
// 138.067 us; speedup vs baseline: 8.7512x; 1.0660x over previous
//
#include <hip/hip_runtime.h>
#include <math.h>
#include <stdint.h>

namespace {

constexpr int Nseq = 1024;
constexpr int Dm = 768;
constexpr int threeD = 2304;
constexpr int Mrows = 8192;
constexpr int Hh = 12;
// scale (1/8) * log2(e)
constexpr float kScaleLog2 = 0.18033688011112042f;

using bf16x8 = __attribute__((ext_vector_type(8))) short;
using f32x4 = __attribute__((ext_vector_type(4))) float;
using f32x16 = __attribute__((ext_vector_type(16))) float;
using us4 = __attribute__((ext_vector_type(4))) unsigned short;

__device__ __forceinline__ unsigned short f2bf(float f) {
  union { float f; uint32_t u; } v;
  v.f = f;
  uint32_t r = v.u + 0x7fffu + ((v.u >> 16) & 1u);
  return (unsigned short)(r >> 16);
}

__device__ __forceinline__ float fexp2(float x) {
#if __has_builtin(__builtin_amdgcn_exp2f)
  return __builtin_amdgcn_exp2f(x);
#else
  float r;
  asm("v_exp_f32 %0, %1\n\ts_nop 0" : "=v"(r) : "v"(x));
  return r;
#endif
}

__device__ __forceinline__ uint32_t cvtpk_bf16(float lo, float hi) {
  uint32_t r;
  asm("v_cvt_pk_bf16_f32 %0, %1, %2" : "=v"(r) : "v"(lo), "v"(hi));
  return r;
}

__device__ __forceinline__ void gload_lds16(const void* g, void* l) {
  __builtin_amdgcn_global_load_lds(
      (const __attribute__((address_space(1))) unsigned int*)(uintptr_t)g,
      (__attribute__((address_space(3))) unsigned int*)(uintptr_t)l, 16, 0, 0);
}

// ---------------------------------------------------------------------------
// fp32 -> bf16 elementwise cast (vectorized 4/thread)
// ---------------------------------------------------------------------------
__global__ __launch_bounds__(256) void cast_f32_bf16(
    const float* __restrict__ in, unsigned short* __restrict__ outp, int n4) {
  int i = blockIdx.x * blockDim.x + threadIdx.x;
  if (i < n4) {
    float4 v = ((const float4*)in)[i];
    us4 u = {f2bf(v.x), f2bf(v.y), f2bf(v.z), f2bf(v.w)};
    ((us4*)outp)[i] = u;
  }
}

// ---------------------------------------------------------------------------
// W[K][N] fp32 -> Wt[N][K] bf16 (32x32 LDS tile transpose)
// ---------------------------------------------------------------------------
__global__ __launch_bounds__(256) void transpose_cast(
    const float* __restrict__ W, unsigned short* __restrict__ Wt, int K, int N) {
  __shared__ unsigned short tile[32][33];
  const int n0 = blockIdx.x * 32, k0 = blockIdx.y * 32;
  const int tx = threadIdx.x & 31, ty = threadIdx.x >> 5;
#pragma unroll
  for (int i = 0; i < 32; i += 8)
    tile[ty + i][tx] = f2bf(W[(size_t)(k0 + ty + i) * N + n0 + tx]);
  __syncthreads();
#pragma unroll
  for (int i = 0; i < 32; i += 8)
    Wt[(size_t)(n0 + ty + i) * K + k0 + tx] = tile[tx][ty + i];
}

// ---------------------------------------------------------------------------
// bf16 MFMA GEMM: C = A[M][K] @ Bt[N][K]^T. 128x128 tile, BK=32, 4 waves.
// MODE 0 (QKV): cols <768 (=Q) scaled by kScaleLog2 -> qk buffer [M][1536];
//   cols 768..1535 (=K) -> qk buffer; cols >=1536 -> V transposed to
//   vtb[(b*12+h)*64+d][1024] bf16 (packed 4-token stores).
// MODE 1 (proj): f32 out [M][768] + bias.
// ---------------------------------------------------------------------------
template <int MODE>
__global__ __launch_bounds__(256) void gemm_bf16(
    const unsigned short* __restrict__ A, const unsigned short* __restrict__ Bt,
    void* __restrict__ C0, void* __restrict__ C1,
    const float* __restrict__ bias, int K) {
  __shared__ unsigned short As[128 * 32];
  __shared__ unsigned short Bs[128 * 32];
  const int tid = threadIdx.x;
  const int wid = tid >> 6;
  const int lane = tid & 63;
  const int l15 = lane & 15, lg = lane >> 4;
  const int row0 = blockIdx.y * 128, col0 = blockIdx.x * 128;
  const int wr = (wid >> 1) * 64, wc = (wid & 1) * 64;
  const int lr = lane >> 2;
  const int lk = (lane & 3) * 8;
  f32x4 acc[4][4] = {};
  for (int k0 = 0; k0 < K; k0 += 32) {
    __syncthreads();
#pragma unroll
    for (int it = 0; it < 2; ++it) {
      const int c = wid * 2 + it;
      gload_lds16(&A[(size_t)(row0 + c * 16 + lr) * K + k0 + lk], &As[c * 512]);
      gload_lds16(&Bt[(size_t)(col0 + c * 16 + lr) * K + k0 + lk], &Bs[c * 512]);
    }
    __syncthreads();
    bf16x8 av[4], bv[4];
#pragma unroll
    for (int m = 0; m < 4; ++m)
      av[m] = *(const bf16x8*)&As[(wr + m * 16 + l15) * 32 + lg * 8];
#pragma unroll
    for (int n = 0; n < 4; ++n)
      bv[n] = *(const bf16x8*)&Bs[(wc + n * 16 + l15) * 32 + lg * 8];
#pragma unroll
    for (int m = 0; m < 4; ++m)
#pragma unroll
      for (int n = 0; n < 4; ++n)
        acc[m][n] =
            __builtin_amdgcn_mfma_f32_16x16x32_bf16(av[m], bv[n], acc[m][n], 0, 0, 0);
  }
  if constexpr (MODE == 1) {
#pragma unroll
    for (int m = 0; m < 4; ++m)
#pragma unroll
      for (int n = 0; n < 4; ++n) {
        const int col = col0 + wc + n * 16 + l15;
#pragma unroll
        for (int rr = 0; rr < 4; ++rr)
          ((float*)C0)[(size_t)(row0 + wr + m * 16 + lg * 4 + rr) * Dm + col] =
              acc[m][n][rr] + bias[col];
      }
  } else if (col0 < 1536) {  // Q/K -> qk buffer, stride 1536; Q pre-scaled
#pragma unroll
    for (int m = 0; m < 4; ++m)
#pragma unroll
      for (int n = 0; n < 4; ++n) {
        const int col = col0 + wc + n * 16 + l15;
        const float qs = (col < 768) ? kScaleLog2 : 1.f;
#pragma unroll
        for (int rr = 0; rr < 4; ++rr)
          ((unsigned short*)C0)[(size_t)(row0 + wr + m * 16 + lg * 4 + rr) * 1536 +
                                col] = f2bf(acc[m][n][rr] * qs);
      }
  } else {  // V -> vtb[(b*12+h)*64+d][1024], 4 consecutive tokens per store
#pragma unroll
    for (int m = 0; m < 4; ++m)
#pragma unroll
      for (int n = 0; n < 4; ++n) {
        const int c = col0 + wc + n * 16 + l15 - 1536;  // h*64+d
        const int row = row0 + wr + m * 16 + lg * 4;    // first of 4 tokens
        const int bb = row >> 10, n0 = row & 1023;
        us4 pk = {f2bf(acc[m][n][0]), f2bf(acc[m][n][1]), f2bf(acc[m][n][2]),
                  f2bf(acc[m][n][3])};
        *(us4*)&((unsigned short*)C1)[((size_t)bb * 768 + c) * 1024 + n0] = pk;
      }
  }
}

// ---------------------------------------------------------------------------
// MFMA flash attention, swapped-operand (T12) structure. 1D grid of 768,
// XCD-chunked decode so each XCD owns 12 (b,h) pairs x 8 q-tiles (K/V stays
// L2-resident per XCD). Block: 128 q-rows, 4 waves x 32 rows.
//   S^T[key][q] = mfma_32x32x16(Kfrag, Qfrag); Q pre-scaled by scale*log2e.
//   Softmax in-register (tree reductions, shfl_xor(,32), defer-max T13).
//   P -> bf16 via v_cvt_pk_bf16_f32 + v_permlane32_swap_b32.
//   O^T[d][q] = mfma(Vtfrag, Pfrag): lane-local rescale/normalize.
// K/Vt double-buffered via global_load_lds, pre-swizzled source chunks.
// ---------------------------------------------------------------------------
__global__ __launch_bounds__(256) void attn_mfma(
    const unsigned short* __restrict__ qkb, const unsigned short* __restrict__ vtb,
    unsigned short* __restrict__ outb) {
  __shared__ unsigned short Ks[2][64 * 64];
  __shared__ unsigned short Vs[2][64 * 64];
  const int tid = threadIdx.x;
  const int wid = tid >> 6, lane = tid & 63;
  const int l31 = lane & 31, hi = lane >> 5;
  // XCD-chunked swizzle: 768 blocks = 8 XCDs x 96
  const int p = blockIdx.x;
  const int l = (p & 7) * 96 + (p >> 3);
  const int qt = l & 7;
  const int hb = l >> 3;
  const int h = hb % Hh, b = hb / Hh;
  const size_t rb = (size_t)b * Nseq;
  const int hoff = h * 64;
  const size_t vbase = ((size_t)b * 768 + hoff) * 1024;

  const int qrow = qt * 128 + wid * 32 + l31;
  bf16x8 Qf[4];
#pragma unroll
  for (int ks = 0; ks < 4; ++ks)
    Qf[ks] = *(const bf16x8*)&qkb[(rb + qrow) * 1536 + hoff + ks * 16 + hi * 8];

  // per-lane staging coords: 2 issues/buffer, 8 chunks (16B) per row
  int strow[2], scol[2];
#pragma unroll
  for (int it = 0; it < 2; ++it) {
    const int ci = it * 256 + wid * 64 + lane;
    const int tr = ci >> 3, cc = ci & 7;
    strow[it] = tr;
    scol[it] = (cc ^ (tr & 7)) * 8;  // pre-swizzled source chunk (shorts)
  }

  auto stage = [&](int kt, int bufi) {
#pragma unroll
    for (int it = 0; it < 2; ++it) {
      const int ldsoff = (it * 256 + wid * 64) * 8;
      gload_lds16(&qkb[(rb + kt * 64 + strow[it]) * 1536 + 768 + hoff + scol[it]],
                  &Ks[bufi][ldsoff]);
      gload_lds16(&vtb[vbase + (size_t)strow[it] * 1024 + kt * 64 + scol[it]],
                  &Vs[bufi][ldsoff]);
    }
  };

  float m_run = -3.0e38f, l_run = 0.f;
  f32x16 o0 = {}, o1 = {};

  stage(0, 0);
  __syncthreads();

  for (int kt = 0; kt < Nseq / 64; ++kt) {
    const int bufi = kt & 1;
    if (kt + 1 < Nseq / 64) stage(kt + 1, bufi ^ 1);
    const unsigned short* ksb = Ks[bufi];
    const unsigned short* vsb = Vs[bufi];
    // S^T = K . Q^T  (2 key-blocks of 32); scores already in exp2 domain
    f32x16 s0 = {}, s1 = {};
    __builtin_amdgcn_s_setprio(1);
#pragma unroll
    for (int ks = 0; ks < 4; ++ks) {
      const int c = 2 * ks + hi;
      {
        const int tr = l31;
        bf16x8 kf = *(const bf16x8*)&ksb[tr * 64 + ((c ^ (tr & 7)) * 8)];
        s0 = __builtin_amdgcn_mfma_f32_32x32x16_bf16(kf, Qf[ks], s0, 0, 0, 0);
      }
      {
        const int tr = l31 + 32;
        bf16x8 kf = *(const bf16x8*)&ksb[tr * 64 + ((c ^ (tr & 7)) * 8)];
        s1 = __builtin_amdgcn_mfma_f32_32x32x16_bf16(kf, Qf[ks], s1, 0, 0, 0);
      }
    }
    __builtin_amdgcn_s_setprio(0);
    // row max: tree reduction (depth ~5), then partner half
    float t[8];
#pragma unroll
    for (int i = 0; i < 8; ++i)
      t[i] = fmaxf(fmaxf(s0[i], s0[i + 8]), fmaxf(s1[i], s1[i + 8]));
#pragma unroll
    for (int st = 4; st >= 1; st >>= 1)
#pragma unroll
      for (int i = 0; i < st; ++i) t[i] = fmaxf(t[i], t[i + st]);
    float mx = fmaxf(t[0], __shfl_xor(t[0], 32));
    const float mn = fmaxf(m_run, mx);
    if (!__all(mn - m_run <= 8.f)) {  // defer-max (T13), log2 domain
      const float al = fexp2(m_run - mn);
#pragma unroll
      for (int i = 0; i < 16; ++i) {
        o0[i] *= al;
        o1[i] *= al;
      }
      l_run *= al;
      m_run = mn;
    }
    const float negm = -m_run;
#pragma unroll
    for (int i = 0; i < 16; ++i) {
      s0[i] = fexp2(s0[i] + negm);
      s1[i] = fexp2(s1[i] + negm);
    }
    // row sum: tree reduction
    float a[8];
#pragma unroll
    for (int i = 0; i < 8; ++i)
      a[i] = (s0[i] + s0[i + 8]) + (s1[i] + s1[i + 8]);
#pragma unroll
    for (int st = 4; st >= 1; st >>= 1)
#pragma unroll
      for (int i = 0; i < st; ++i) a[i] += a[i + st];
    l_run += a[0] + __shfl_xor(a[0], 32);
    // pack P into A/B-frag bf16 layout: 16 cvt_pk + 8 permlane32_swap
    bf16x8 Pf[4];
#pragma unroll
    for (int ks = 0; ks < 4; ++ks) {
      const f32x16 sv = (ks >> 1) ? s1 : s0;
      const int e0 = 8 * (ks & 1);
      uint32_t pe01 = cvtpk_bf16(sv[e0 + 0], sv[e0 + 1]);
      uint32_t pe23 = cvtpk_bf16(sv[e0 + 2], sv[e0 + 3]);
      uint32_t po01 = cvtpk_bf16(sv[e0 + 4], sv[e0 + 5]);
      uint32_t po23 = cvtpk_bf16(sv[e0 + 6], sv[e0 + 7]);
      asm("v_permlane32_swap_b32 %0, %1" : "+v"(pe01), "+v"(po01));
      asm("v_permlane32_swap_b32 %0, %1" : "+v"(pe23), "+v"(po23));
      union {
        uint32_t w[4];
        bf16x8 v;
      } u;
      u.w[0] = pe01;  // keys 16ks+{0,1}
      u.w[1] = pe23;  // keys 16ks+{2,3}
      u.w[2] = po01;  // keys 16ks+{4,5}
      u.w[3] = po23;  // keys 16ks+{6,7}
      Pf[ks] = u.v;
    }
    // O^T += V^T . P^T  (2 d-blocks of 32)
    __builtin_amdgcn_s_setprio(1);
#pragma unroll
    for (int ks = 0; ks < 4; ++ks) {
      const int c = 2 * ks + hi;
      {
        const int tr = l31;
        bf16x8 vf = *(const bf16x8*)&vsb[tr * 64 + ((c ^ (tr & 7)) * 8)];
        o0 = __builtin_amdgcn_mfma_f32_32x32x16_bf16(vf, Pf[ks], o0, 0, 0, 0);
      }
      {
        const int tr = l31 + 32;
        bf16x8 vf = *(const bf16x8*)&vsb[tr * 64 + ((c ^ (tr & 7)) * 8)];
        o1 = __builtin_amdgcn_mfma_f32_32x32x16_bf16(vf, Pf[ks], o1, 0, 0, 0);
      }
    }
    __builtin_amdgcn_s_setprio(0);
    __syncthreads();
  }
  // epilogue: lane owns q-row; d = (reg&3) + 8*(reg>>2) + 4*hi (+32 for o1)
  const float linv = 1.f / l_run;
  const size_t obase = (size_t)(rb + qrow) * Dm + hoff;
#pragma unroll
  for (int g = 0; g < 4; ++g) {
    us4 a4 = {f2bf(o0[g * 4 + 0] * linv), f2bf(o0[g * 4 + 1] * linv),
              f2bf(o0[g * 4 + 2] * linv), f2bf(o0[g * 4 + 3] * linv)};
    *(us4*)&outb[obase + g * 8 + hi * 4] = a4;
    us4 b4 = {f2bf(o1[g * 4 + 0] * linv), f2bf(o1[g * 4 + 1] * linv),
              f2bf(o1[g * 4 + 2] * linv), f2bf(o1[g * 4 + 3] * linv)};
    *(us4*)&outb[obase + 32 + g * 8 + hi * 4] = b4;
  }
}

}  // namespace

extern "C" void kernel_launch(void* const* d_in, const int* in_sizes, int n_in,
                              void* d_out, int out_size, void* d_ws,
                              size_t ws_size, hipStream_t stream) {
  (void)in_sizes;
  (void)n_in;
  (void)out_size;
  (void)ws_size;
  const float* x = (const float*)d_in[0];      // [8192][768]
  const float* Wqkv = (const float*)d_in[1];   // [768][2304]
  const float* Wproj = (const float*)d_in[2];  // [768][768]
  const float* bproj = (const float*)d_in[3];  // [768]
  float* out = (float*)d_out;                  // [8192][768]

  char* w = (char*)d_ws;
  unsigned short* xb = (unsigned short*)w;      // 12.58 MB
  w += (size_t)Mrows * Dm * 2;
  unsigned short* wqkvt = (unsigned short*)w;   // 3.54 MB
  w += (size_t)threeD * Dm * 2;
  unsigned short* wprojt = (unsigned short*)w;  // 1.18 MB
  w += (size_t)Dm * Dm * 2;
  unsigned short* qkb = (unsigned short*)w;     // [8192][1536] 25.17 MB
  w += (size_t)Mrows * 1536 * 2;
  unsigned short* vtb = (unsigned short*)w;     // [96*64][1024] 12.58 MB
  w += (size_t)96 * 64 * 1024 * 2;
  unsigned short* attnb = (unsigned short*)w;   // 12.58 MB

  cast_f32_bf16<<<(Mrows * Dm / 4 + 255) / 256, 256, 0, stream>>>(
      x, xb, Mrows * Dm / 4);
  transpose_cast<<<dim3(threeD / 32, Dm / 32), 256, 0, stream>>>(
      Wqkv, wqkvt, Dm, threeD);
  transpose_cast<<<dim3(Dm / 32, Dm / 32), 256, 0, stream>>>(Wproj, wprojt, Dm, Dm);
  // qkv = x @ Wqkv; Q (pre-scaled) / K -> qkb, V -> vtb (transposed)
  gemm_bf16<0><<<dim3(threeD / 128, Mrows / 128), 256, 0, stream>>>(
      xb, wqkvt, qkb, vtb, nullptr, Dm);
  // flash attention (128 q-rows per block, XCD-chunked 1D grid)
  attn_mfma<<<dim3(768), 256, 0, stream>>>(qkb, vtb, attnb);
  // out = attn @ Wproj + bias (f32 out)
  gemm_bf16<1><<<dim3(Dm / 128, Mrows / 128), 256, 0, stream>>>(
      attnb, wprojt, out, nullptr, bproj, Dm);
}

// Round 6
// 122.627 us; speedup vs baseline: 9.8531x; 1.1259x over previous
//
#include <hip/hip_runtime.h>
#include <math.h>
#include <stdint.h>

namespace {

constexpr int Nseq = 1024;
constexpr int Dm = 768;
constexpr int threeD = 2304;
constexpr int Mrows = 8192;
constexpr int Hh = 12;
// scale (1/8) * log2(e)
constexpr float kScaleLog2 = 0.18033688011112042f;

using bf16x8 = __attribute__((ext_vector_type(8))) short;
using f32x4 = __attribute__((ext_vector_type(4))) float;
using f32x16 = __attribute__((ext_vector_type(16))) float;
using us4 = __attribute__((ext_vector_type(4))) unsigned short;

__device__ __forceinline__ unsigned short f2bf(float f) {
  union { float f; uint32_t u; } v;
  v.f = f;
  uint32_t r = v.u + 0x7fffu + ((v.u >> 16) & 1u);
  return (unsigned short)(r >> 16);
}

__device__ __forceinline__ float fexp2(float x) {
#if __has_builtin(__builtin_amdgcn_exp2f)
  return __builtin_amdgcn_exp2f(x);
#else
  float r;
  asm("v_exp_f32 %0, %1\n\ts_nop 0" : "=v"(r) : "v"(x));
  return r;
#endif
}

__device__ __forceinline__ uint32_t cvtpk_bf16(float lo, float hi) {
  uint32_t r;
  asm("v_cvt_pk_bf16_f32 %0, %1, %2" : "=v"(r) : "v"(lo), "v"(hi));
  return r;
}

__device__ __forceinline__ void gload_lds16(const void* g, void* l) {
  __builtin_amdgcn_global_load_lds(
      (const __attribute__((address_space(1))) unsigned int*)(uintptr_t)g,
      (__attribute__((address_space(3))) unsigned int*)(uintptr_t)l, 16, 0, 0);
}

// ---------------------------------------------------------------------------
// fp32 -> bf16 elementwise cast (vectorized 4/thread)
// ---------------------------------------------------------------------------
__global__ __launch_bounds__(256) void cast_f32_bf16(
    const float* __restrict__ in, unsigned short* __restrict__ outp, int n4) {
  int i = blockIdx.x * blockDim.x + threadIdx.x;
  if (i < n4) {
    float4 v = ((const float4*)in)[i];
    us4 u = {f2bf(v.x), f2bf(v.y), f2bf(v.z), f2bf(v.w)};
    ((us4*)outp)[i] = u;
  }
}

// ---------------------------------------------------------------------------
// W[K][N] fp32 -> Wt[N][K] bf16 (32x32 LDS tile transpose)
// ---------------------------------------------------------------------------
__global__ __launch_bounds__(256) void transpose_cast(
    const float* __restrict__ W, unsigned short* __restrict__ Wt, int K, int N) {
  __shared__ unsigned short tile[32][33];
  const int n0 = blockIdx.x * 32, k0 = blockIdx.y * 32;
  const int tx = threadIdx.x & 31, ty = threadIdx.x >> 5;
#pragma unroll
  for (int i = 0; i < 32; i += 8)
    tile[ty + i][tx] = f2bf(W[(size_t)(k0 + ty + i) * N + n0 + tx]);
  __syncthreads();
#pragma unroll
  for (int i = 0; i < 32; i += 8)
    Wt[(size_t)(n0 + ty + i) * K + k0 + tx] = tile[tx][ty + i];
}

// ---------------------------------------------------------------------------
// bf16 MFMA GEMM: C = A[M][K] @ Bt[N][K]^T. 128x128 tile, BK=32, 4 waves,
// double-buffered LDS with T3-minimum pipeline: issue stage(t+1) BEFORE
// compute(t); one vmcnt(0)+barrier per k-step -> global latency hides under
// the 16-MFMA cluster. 1D grid, bijective XCD-chunked swizzle (NWGd8 = nwg/8)
// so each XCD owns consecutive row-panels (A panel + whole B L2-resident).
// MODE 0 (QKV, NCOLS=18): cols <768 (Q, pre-scaled by scale*log2e) and
//   768..1535 (K) -> qkb [M][1536] bf16; cols >=1536 -> V transposed to
//   vtb[(b*12+h)*64+d][1024] bf16 (packed 4-token stores).
// MODE 1 (proj, NCOLS=6): f32 out [M][768] + bias.
// ---------------------------------------------------------------------------
template <int MODE, int NCOLS>
__global__ __launch_bounds__(256) void gemm_bf16(
    const unsigned short* __restrict__ A, const unsigned short* __restrict__ Bt,
    void* __restrict__ C0, void* __restrict__ C1,
    const float* __restrict__ bias, int K) {
  __shared__ unsigned short As[2][128 * 32];
  __shared__ unsigned short Bs[2][128 * 32];
  const int tid = threadIdx.x;
  const int wid = tid >> 6;
  const int lane = tid & 63;
  const int l15 = lane & 15, lg = lane >> 4;
  // XCD-chunked bijective swizzle (gridDim.x % 8 == 0)
  const int p = blockIdx.x;
  const int cpx = gridDim.x >> 3;
  const int l = (p & 7) * cpx + (p >> 3);
  const int row0 = (l / NCOLS) * 128, col0 = (l % NCOLS) * 128;
  const int wr = (wid >> 1) * 64, wc = (wid & 1) * 64;
  const int lr = lane >> 2;
  const int lk = (lane & 3) * 8;

  auto stage = [&](int k0, int bufi) {
#pragma unroll
    for (int it = 0; it < 2; ++it) {
      const int c = wid * 2 + it;  // 16-row chunk 0..7
      gload_lds16(&A[(size_t)(row0 + c * 16 + lr) * K + k0 + lk],
                  &As[bufi][c * 512]);
      gload_lds16(&Bt[(size_t)(col0 + c * 16 + lr) * K + k0 + lk],
                  &Bs[bufi][c * 512]);
    }
  };

  f32x4 acc[4][4] = {};
  stage(0, 0);
  __syncthreads();
  const int nt = K / 32;
  for (int t = 0; t < nt; ++t) {
    const int cur = t & 1;
    if (t + 1 < nt) stage((t + 1) * 32, cur ^ 1);  // prefetch under compute
    bf16x8 av[4], bv[4];
#pragma unroll
    for (int m = 0; m < 4; ++m)
      av[m] = *(const bf16x8*)&As[cur][(wr + m * 16 + l15) * 32 + lg * 8];
#pragma unroll
    for (int n = 0; n < 4; ++n)
      bv[n] = *(const bf16x8*)&Bs[cur][(wc + n * 16 + l15) * 32 + lg * 8];
#pragma unroll
    for (int m = 0; m < 4; ++m)
#pragma unroll
      for (int n = 0; n < 4; ++n)
        acc[m][n] =
            __builtin_amdgcn_mfma_f32_16x16x32_bf16(av[m], bv[n], acc[m][n], 0, 0, 0);
    __syncthreads();  // drains vmcnt(0): next buffer ready, cur reads done
  }
  if constexpr (MODE == 1) {
#pragma unroll
    for (int m = 0; m < 4; ++m)
#pragma unroll
      for (int n = 0; n < 4; ++n) {
        const int col = col0 + wc + n * 16 + l15;
#pragma unroll
        for (int rr = 0; rr < 4; ++rr)
          ((float*)C0)[(size_t)(row0 + wr + m * 16 + lg * 4 + rr) * Dm + col] =
              acc[m][n][rr] + bias[col];
      }
  } else if (col0 < 1536) {  // Q/K -> qk buffer, stride 1536; Q pre-scaled
#pragma unroll
    for (int m = 0; m < 4; ++m)
#pragma unroll
      for (int n = 0; n < 4; ++n) {
        const int col = col0 + wc + n * 16 + l15;
        const float qs = (col < 768) ? kScaleLog2 : 1.f;
#pragma unroll
        for (int rr = 0; rr < 4; ++rr)
          ((unsigned short*)C0)[(size_t)(row0 + wr + m * 16 + lg * 4 + rr) * 1536 +
                                col] = f2bf(acc[m][n][rr] * qs);
      }
  } else {  // V -> vtb[(b*12+h)*64+d][1024], 4 consecutive tokens per store
#pragma unroll
    for (int m = 0; m < 4; ++m)
#pragma unroll
      for (int n = 0; n < 4; ++n) {
        const int c = col0 + wc + n * 16 + l15 - 1536;  // h*64+d
        const int row = row0 + wr + m * 16 + lg * 4;    // first of 4 tokens
        const int bb = row >> 10, n0 = row & 1023;
        us4 pk = {f2bf(acc[m][n][0]), f2bf(acc[m][n][1]), f2bf(acc[m][n][2]),
                  f2bf(acc[m][n][3])};
        *(us4*)&((unsigned short*)C1)[((size_t)bb * 768 + c) * 1024 + n0] = pk;
      }
  }
}

// ---------------------------------------------------------------------------
// MFMA flash attention, swapped-operand (T12) structure. 1D grid of 768,
// XCD-chunked decode so each XCD owns 12 (b,h) pairs x 8 q-tiles (K/V stays
// L2-resident per XCD). Block: 128 q-rows, 4 waves x 32 rows.
//   S^T[key][q] = mfma_32x32x16(Kfrag, Qfrag); Q pre-scaled by scale*log2e.
//   Softmax in-register (tree reductions, shfl_xor(,32), defer-max T13).
//   P -> bf16 via v_cvt_pk_bf16_f32 + v_permlane32_swap_b32.
//   O^T[d][q] = mfma(Vtfrag, Pfrag): lane-local rescale/normalize.
// K/Vt double-buffered via global_load_lds, pre-swizzled source chunks.
// ---------------------------------------------------------------------------
__global__ __launch_bounds__(256) void attn_mfma(
    const unsigned short* __restrict__ qkb, const unsigned short* __restrict__ vtb,
    unsigned short* __restrict__ outb) {
  __shared__ unsigned short Ks[2][64 * 64];
  __shared__ unsigned short Vs[2][64 * 64];
  const int tid = threadIdx.x;
  const int wid = tid >> 6, lane = tid & 63;
  const int l31 = lane & 31, hi = lane >> 5;
  // XCD-chunked swizzle: 768 blocks = 8 XCDs x 96
  const int p = blockIdx.x;
  const int l = (p & 7) * 96 + (p >> 3);
  const int qt = l & 7;
  const int hb = l >> 3;
  const int h = hb % Hh, b = hb / Hh;
  const size_t rb = (size_t)b * Nseq;
  const int hoff = h * 64;
  const size_t vbase = ((size_t)b * 768 + hoff) * 1024;

  const int qrow = qt * 128 + wid * 32 + l31;
  bf16x8 Qf[4];
#pragma unroll
  for (int ks = 0; ks < 4; ++ks)
    Qf[ks] = *(const bf16x8*)&qkb[(rb + qrow) * 1536 + hoff + ks * 16 + hi * 8];

  // per-lane staging coords: 2 issues/buffer, 8 chunks (16B) per row
  int strow[2], scol[2];
#pragma unroll
  for (int it = 0; it < 2; ++it) {
    const int ci = it * 256 + wid * 64 + lane;
    const int tr = ci >> 3, cc = ci & 7;
    strow[it] = tr;
    scol[it] = (cc ^ (tr & 7)) * 8;  // pre-swizzled source chunk (shorts)
  }

  auto stage = [&](int kt, int bufi) {
#pragma unroll
    for (int it = 0; it < 2; ++it) {
      const int ldsoff = (it * 256 + wid * 64) * 8;
      gload_lds16(&qkb[(rb + kt * 64 + strow[it]) * 1536 + 768 + hoff + scol[it]],
                  &Ks[bufi][ldsoff]);
      gload_lds16(&vtb[vbase + (size_t)strow[it] * 1024 + kt * 64 + scol[it]],
                  &Vs[bufi][ldsoff]);
    }
  };

  float m_run = -3.0e38f, l_run = 0.f;
  f32x16 o0 = {}, o1 = {};

  stage(0, 0);
  __syncthreads();

  for (int kt = 0; kt < Nseq / 64; ++kt) {
    const int bufi = kt & 1;
    if (kt + 1 < Nseq / 64) stage(kt + 1, bufi ^ 1);
    const unsigned short* ksb = Ks[bufi];
    const unsigned short* vsb = Vs[bufi];
    // S^T = K . Q^T  (2 key-blocks of 32); scores already in exp2 domain
    f32x16 s0 = {}, s1 = {};
    __builtin_amdgcn_s_setprio(1);
#pragma unroll
    for (int ks = 0; ks < 4; ++ks) {
      const int c = 2 * ks + hi;
      {
        const int tr = l31;
        bf16x8 kf = *(const bf16x8*)&ksb[tr * 64 + ((c ^ (tr & 7)) * 8)];
        s0 = __builtin_amdgcn_mfma_f32_32x32x16_bf16(kf, Qf[ks], s0, 0, 0, 0);
      }
      {
        const int tr = l31 + 32;
        bf16x8 kf = *(const bf16x8*)&ksb[tr * 64 + ((c ^ (tr & 7)) * 8)];
        s1 = __builtin_amdgcn_mfma_f32_32x32x16_bf16(kf, Qf[ks], s1, 0, 0, 0);
      }
    }
    __builtin_amdgcn_s_setprio(0);
    // row max: tree reduction (depth ~5), then partner half
    float t[8];
#pragma unroll
    for (int i = 0; i < 8; ++i)
      t[i] = fmaxf(fmaxf(s0[i], s0[i + 8]), fmaxf(s1[i], s1[i + 8]));
#pragma unroll
    for (int st = 4; st >= 1; st >>= 1)
#pragma unroll
      for (int i = 0; i < st; ++i) t[i] = fmaxf(t[i], t[i + st]);
    float mx = fmaxf(t[0], __shfl_xor(t[0], 32));
    const float mn = fmaxf(m_run, mx);
    if (!__all(mn - m_run <= 8.f)) {  // defer-max (T13), log2 domain
      const float al = fexp2(m_run - mn);
#pragma unroll
      for (int i = 0; i < 16; ++i) {
        o0[i] *= al;
        o1[i] *= al;
      }
      l_run *= al;
      m_run = mn;
    }
    const float negm = -m_run;
#pragma unroll
    for (int i = 0; i < 16; ++i) {
      s0[i] = fexp2(s0[i] + negm);
      s1[i] = fexp2(s1[i] + negm);
    }
    // row sum: tree reduction
    float a[8];
#pragma unroll
    for (int i = 0; i < 8; ++i)
      a[i] = (s0[i] + s0[i + 8]) + (s1[i] + s1[i + 8]);
#pragma unroll
    for (int st = 4; st >= 1; st >>= 1)
#pragma unroll
      for (int i = 0; i < st; ++i) a[i] += a[i + st];
    l_run += a[0] + __shfl_xor(a[0], 32);
    // pack P into A/B-frag bf16 layout: 16 cvt_pk + 8 permlane32_swap
    bf16x8 Pf[4];
#pragma unroll
    for (int ks = 0; ks < 4; ++ks) {
      const f32x16 sv = (ks >> 1) ? s1 : s0;
      const int e0 = 8 * (ks & 1);
      uint32_t pe01 = cvtpk_bf16(sv[e0 + 0], sv[e0 + 1]);
      uint32_t pe23 = cvtpk_bf16(sv[e0 + 2], sv[e0 + 3]);
      uint32_t po01 = cvtpk_bf16(sv[e0 + 4], sv[e0 + 5]);
      uint32_t po23 = cvtpk_bf16(sv[e0 + 6], sv[e0 + 7]);
      asm("v_permlane32_swap_b32 %0, %1" : "+v"(pe01), "+v"(po01));
      asm("v_permlane32_swap_b32 %0, %1" : "+v"(pe23), "+v"(po23));
      union {
        uint32_t w[4];
        bf16x8 v;
      } u;
      u.w[0] = pe01;  // keys 16ks+{0,1}
      u.w[1] = pe23;  // keys 16ks+{2,3}
      u.w[2] = po01;  // keys 16ks+{4,5}
      u.w[3] = po23;  // keys 16ks+{6,7}
      Pf[ks] = u.v;
    }
    // O^T += V^T . P^T  (2 d-blocks of 32)
    __builtin_amdgcn_s_setprio(1);
#pragma unroll
    for (int ks = 0; ks < 4; ++ks) {
      const int c = 2 * ks + hi;
      {
        const int tr = l31;
        bf16x8 vf = *(const bf16x8*)&vsb[tr * 64 + ((c ^ (tr & 7)) * 8)];
        o0 = __builtin_amdgcn_mfma_f32_32x32x16_bf16(vf, Pf[ks], o0, 0, 0, 0);
      }
      {
        const int tr = l31 + 32;
        bf16x8 vf = *(const bf16x8*)&vsb[tr * 64 + ((c ^ (tr & 7)) * 8)];
        o1 = __builtin_amdgcn_mfma_f32_32x32x16_bf16(vf, Pf[ks], o1, 0, 0, 0);
      }
    }
    __builtin_amdgcn_s_setprio(0);
    __syncthreads();
  }
  // epilogue: lane owns q-row; d = (reg&3) + 8*(reg>>2) + 4*hi (+32 for o1)
  const float linv = 1.f / l_run;
  const size_t obase = (size_t)(rb + qrow) * Dm + hoff;
#pragma unroll
  for (int g = 0; g < 4; ++g) {
    us4 a4 = {f2bf(o0[g * 4 + 0] * linv), f2bf(o0[g * 4 + 1] * linv),
              f2bf(o0[g * 4 + 2] * linv), f2bf(o0[g * 4 + 3] * linv)};
    *(us4*)&outb[obase + g * 8 + hi * 4] = a4;
    us4 b4 = {f2bf(o1[g * 4 + 0] * linv), f2bf(o1[g * 4 + 1] * linv),
              f2bf(o1[g * 4 + 2] * linv), f2bf(o1[g * 4 + 3] * linv)};
    *(us4*)&outb[obase + 32 + g * 8 + hi * 4] = b4;
  }
}

}  // namespace

extern "C" void kernel_launch(void* const* d_in, const int* in_sizes, int n_in,
                              void* d_out, int out_size, void* d_ws,
                              size_t ws_size, hipStream_t stream) {
  (void)in_sizes;
  (void)n_in;
  (void)out_size;
  (void)ws_size;
  const float* x = (const float*)d_in[0];      // [8192][768]
  const float* Wqkv = (const float*)d_in[1];   // [768][2304]
  const float* Wproj = (const float*)d_in[2];  // [768][768]
  const float* bproj = (const float*)d_in[3];  // [768]
  float* out = (float*)d_out;                  // [8192][768]

  char* w = (char*)d_ws;
  unsigned short* xb = (unsigned short*)w;      // 12.58 MB
  w += (size_t)Mrows * Dm * 2;
  unsigned short* wqkvt = (unsigned short*)w;   // 3.54 MB
  w += (size_t)threeD * Dm * 2;
  unsigned short* wprojt = (unsigned short*)w;  // 1.18 MB
  w += (size_t)Dm * Dm * 2;
  unsigned short* qkb = (unsigned short*)w;     // [8192][1536] 25.17 MB
  w += (size_t)Mrows * 1536 * 2;
  unsigned short* vtb = (unsigned short*)w;     // [96*64][1024] 12.58 MB
  w += (size_t)96 * 64 * 1024 * 2;
  unsigned short* attnb = (unsigned short*)w;   // 12.58 MB

  cast_f32_bf16<<<(Mrows * Dm / 4 + 255) / 256, 256, 0, stream>>>(
      x, xb, Mrows * Dm / 4);
  transpose_cast<<<dim3(threeD / 32, Dm / 32), 256, 0, stream>>>(
      Wqkv, wqkvt, Dm, threeD);
  transpose_cast<<<dim3(Dm / 32, Dm / 32), 256, 0, stream>>>(Wproj, wprojt, Dm, Dm);
  // qkv = x @ Wqkv; Q (pre-scaled) / K -> qkb, V -> vtb (transposed)
  gemm_bf16<0, 18><<<dim3(1152), 256, 0, stream>>>(
      xb, wqkvt, qkb, vtb, nullptr, Dm);
  // flash attention (128 q-rows per block, XCD-chunked 1D grid)
  attn_mfma<<<dim3(768), 256, 0, stream>>>(qkb, vtb, attnb);
  // out = attn @ Wproj + bias (f32 out)
  gemm_bf16<1, 6><<<dim3(384), 256, 0, stream>>>(
      attnb, wprojt, out, nullptr, bproj, Dm);
}